// Round 1
// baseline (359.111 us; speedup 1.0000x reference)
//
#include <hip/hip_runtime.h>
#include <math.h>

namespace {
constexpr int kB = 2, kH = 16, kS = 2048, kD = 64, kC = 64;
constexpr int kNC = kS / kC;          // 32 chunks
constexpr float kScale = 0.125f;      // 1/sqrt(64)
}

// ---------------------------------------------------------------------------
// Pass 1: per-chunk partial state A_c[d][e] = sum_j gamma^(C-1-j) k[j][d] v[j][e]
// grid = B*H*NC blocks, 256 threads
// ---------------------------------------------------------------------------
__global__ __launch_bounds__(256) void ret_partial(const float* __restrict__ K,
                                                   const float* __restrict__ V,
                                                   float* __restrict__ A) {
  const int idx = blockIdx.x;               // (b*H + h)*NC + c
  const int h = (idx / kNC) % kH;
  const int t = threadIdx.x;

  __shared__ float ks[kC * kD];
  __shared__ float vs[kC * kD];
  __shared__ float pt[kC + 1];

  const size_t gbase = (size_t)idx * (kC * kD);
  {
    const float4* gk = (const float4*)(K + gbase);
    const float4* gv = (const float4*)(V + gbase);
#pragma unroll
    for (int n = 0; n < 4; ++n) {
      ((float4*)ks)[t + 256 * n] = gk[t + 256 * n];
      ((float4*)vs)[t + 256 * n] = gv[t + 256 * n];
    }
  }
  const float log2g = log2f(1.0f - exp2f(-5.0f - (float)h));
  if (t <= kC) pt[t] = exp2f((float)t * log2g);
  __syncthreads();

  const int d = t >> 2;
  const int e0 = (t & 3) * 16;
  float acc[16];
#pragma unroll
  for (int m = 0; m < 16; ++m) acc[m] = 0.0f;

  for (int j = 0; j < kC; ++j) {
    const float wk = pt[kC - 1 - j] * ks[j * kD + d];
    const float4* vr = (const float4*)(vs + j * kD + e0);
#pragma unroll
    for (int m = 0; m < 4; ++m) {
      float4 vv = vr[m];
      acc[4*m+0] += wk * vv.x;
      acc[4*m+1] += wk * vv.y;
      acc[4*m+2] += wk * vv.z;
      acc[4*m+3] += wk * vv.w;
    }
  }

  float4* Ab = (float4*)(A + (size_t)idx * (kD * kD) + d * kD + e0);
#pragma unroll
  for (int m = 0; m < 4; ++m)
    Ab[m] = make_float4(acc[4*m+0], acc[4*m+1], acc[4*m+2], acc[4*m+3]);
}

// ---------------------------------------------------------------------------
// Pass 2: in-place scan.  After: A[bh][c] = P_c (state BEFORE chunk c)
// P_0 = 0 ; P_{c+1} = gamma^C * P_c + A_c
// grid = B*H blocks, 256 threads (each owns 16 contiguous state floats)
// ---------------------------------------------------------------------------
__global__ __launch_bounds__(256) void ret_scan(float* __restrict__ A) {
  const int bh = blockIdx.x;
  const int h = bh % kH;
  const int t = threadIdx.x;
  const float log2g = log2f(1.0f - exp2f(-5.0f - (float)h));
  const float gC = exp2f((float)kC * log2g);

  float4 s[4];
#pragma unroll
  for (int m = 0; m < 4; ++m) s[m] = make_float4(0.f, 0.f, 0.f, 0.f);

  float4* base = (float4*)A + (size_t)bh * kNC * (kD * kD / 4) + t * 4;
  for (int c = 0; c < kNC; ++c) {
    float4* p = base + c * (kD * kD / 4);
    float4 a[4];
#pragma unroll
    for (int m = 0; m < 4; ++m) a[m] = p[m];
#pragma unroll
    for (int m = 0; m < 4; ++m) p[m] = s[m];
#pragma unroll
    for (int m = 0; m < 4; ++m) {
      s[m].x = gC * s[m].x + a[m].x;
      s[m].y = gC * s[m].y + a[m].y;
      s[m].z = gC * s[m].z + a[m].z;
      s[m].w = gC * s[m].w + a[m].w;
    }
  }
}

// ---------------------------------------------------------------------------
// Pass 3: out = scale * ( gamma^(ii+1) * q . P   +   causal-decayed QK^T V )
// grid = B*H*NC blocks, 256 threads: thread t -> row i = t>>2, e-slice (t&3)*16
// ---------------------------------------------------------------------------
__global__ __launch_bounds__(256) void ret_out(const float* __restrict__ Q,
                                               const float* __restrict__ K,
                                               const float* __restrict__ V,
                                               const float* __restrict__ P,
                                               float* __restrict__ O) {
  const int idx = blockIdx.x;
  const int h = (idx / kNC) % kH;
  const int t = threadIdx.x;

  __shared__ float ks[kC * kD];
  __shared__ float vs[kC * kD];
  __shared__ float Ps[kD * kD];
  __shared__ float ss[kC * 65];   // padded scores; first 4096 floats also q-staging
  __shared__ float pt[kC + 1];

  const size_t gbase = (size_t)idx * (kC * kD);
  {
    const float4* gq = (const float4*)(Q + gbase);
    const float4* gk = (const float4*)(K + gbase);
    const float4* gv = (const float4*)(V + gbase);
    const float4* gp = (const float4*)(P + (size_t)idx * (kD * kD));
#pragma unroll
    for (int n = 0; n < 4; ++n) {
      ((float4*)ss)[t + 256*n] = gq[t + 256*n];
      ((float4*)ks)[t + 256*n] = gk[t + 256*n];
      ((float4*)vs)[t + 256*n] = gv[t + 256*n];
      ((float4*)Ps)[t + 256*n] = gp[t + 256*n];
    }
  }
  const float log2g = log2f(1.0f - exp2f(-5.0f - (float)h));
  if (t <= kC) pt[t] = exp2f((float)t * log2g);
  __syncthreads();

  const int i = t >> 2;
  const int e0 = (t & 3) * 16;

  // q row -> registers (fully static indexing)
  float qreg[kD];
#pragma unroll
  for (int n = 0; n < 16; ++n) {
    float4 f = ((const float4*)ss)[i * 16 + n];
    qreg[4*n+0] = f.x; qreg[4*n+1] = f.y; qreg[4*n+2] = f.z; qreg[4*n+3] = f.w;
  }

  float acc[16];
#pragma unroll
  for (int m = 0; m < 16; ++m) acc[m] = 0.0f;

  // Phase 0: inter-chunk  acc = q . P
#pragma unroll
  for (int d = 0; d < kD; ++d) {
    const float wq = qreg[d];
    const float4* pr = (const float4*)(Ps + d * kD + e0);
#pragma unroll
    for (int m = 0; m < 4; ++m) {
      float4 pv = pr[m];
      acc[4*m+0] += wq * pv.x;
      acc[4*m+1] += wq * pv.y;
      acc[4*m+2] += wq * pv.z;
      acc[4*m+3] += wq * pv.w;
    }
  }
  {
    const float wI = pt[i + 1];
#pragma unroll
    for (int m = 0; m < 16; ++m) acc[m] *= wI;
  }

  __syncthreads();   // all q reads from ss done before overwriting with scores

  // Phase A: causal decayed scores -> ss (stride 65, conflict-free)
  {
    const int j0 = (t & 3) * 16;
    for (int jn = 0; jn < 16; ++jn) {
      const int j = j0 + jn;
      float dot = 0.0f;
      const float4* kr = (const float4*)(ks + j * kD);
#pragma unroll
      for (int d4 = 0; d4 < 16; ++d4) {
        float4 kk = kr[d4];
        dot += qreg[4*d4+0]*kk.x + qreg[4*d4+1]*kk.y
             + qreg[4*d4+2]*kk.z + qreg[4*d4+3]*kk.w;
      }
      ss[i * 65 + j] = (j <= i) ? dot * pt[i - j] : 0.0f;
    }
  }
  __syncthreads();

  // Phase B: PV accumulate (wave-uniform bound; zeros above diagonal)
  {
    const int jmax = i | 15;
    for (int j = 0; j <= jmax; ++j) {
      const float w = ss[i * 65 + j];
      const float4* vr = (const float4*)(vs + j * kD + e0);
#pragma unroll
      for (int m = 0; m < 4; ++m) {
        float4 vv = vr[m];
        acc[4*m+0] += w * vv.x;
        acc[4*m+1] += w * vv.y;
        acc[4*m+2] += w * vv.z;
        acc[4*m+3] += w * vv.w;
      }
    }
  }

  float4* ob = (float4*)(O + gbase + i * kD + e0);
#pragma unroll
  for (int m = 0; m < 4; ++m)
    ob[m] = make_float4(kScale * acc[4*m+0], kScale * acc[4*m+1],
                        kScale * acc[4*m+2], kScale * acc[4*m+3]);
}

// ---------------------------------------------------------------------------
// Fallback (no workspace needed): one block per (b,h) walks all chunks with
// the state held in LDS.  Used only if ws_size is too small.
// ---------------------------------------------------------------------------
__global__ __launch_bounds__(256) void ret_fallback(const float* __restrict__ Q,
                                                    const float* __restrict__ K,
                                                    const float* __restrict__ V,
                                                    float* __restrict__ O) {
  const int bh = blockIdx.x;
  const int h = bh % kH;
  const int t = threadIdx.x;

  __shared__ float ks[kC * kD];
  __shared__ float vs[kC * kD];
  __shared__ float St[kD * kD];
  __shared__ float ss[kC * 65];
  __shared__ float pt[kC + 1];

  const float log2g = log2f(1.0f - exp2f(-5.0f - (float)h));
  const float gC = exp2f((float)kC * log2g);
  if (t <= kC) pt[t] = exp2f((float)t * log2g);
#pragma unroll
  for (int n = 0; n < 4; ++n) ((float4*)St)[t + 256*n] = make_float4(0.f,0.f,0.f,0.f);
  __syncthreads();

  const int i = t >> 2;          // row index; doubles as state row d for update
  const int e0 = (t & 3) * 16;

  for (int c = 0; c < kNC; ++c) {
    const size_t gbase = ((size_t)bh * kS + (size_t)c * kC) * kD;
#pragma unroll
    for (int n = 0; n < 4; ++n) {
      ((float4*)ks)[t + 256*n] = ((const float4*)(K + gbase))[t + 256*n];
      ((float4*)vs)[t + 256*n] = ((const float4*)(V + gbase))[t + 256*n];
    }
    float qreg[kD];
#pragma unroll
    for (int n = 0; n < 16; ++n) {
      float4 f = ((const float4*)(Q + gbase + (size_t)i * kD))[n];
      qreg[4*n+0]=f.x; qreg[4*n+1]=f.y; qreg[4*n+2]=f.z; qreg[4*n+3]=f.w;
    }
    __syncthreads();

    float acc[16];
#pragma unroll
    for (int m = 0; m < 16; ++m) acc[m] = 0.0f;
#pragma unroll
    for (int d = 0; d < kD; ++d) {
      const float wq = qreg[d];
      const float4* pr = (const float4*)(St + d * kD + e0);
#pragma unroll
      for (int m = 0; m < 4; ++m) {
        float4 pv = pr[m];
        acc[4*m+0]+=wq*pv.x; acc[4*m+1]+=wq*pv.y; acc[4*m+2]+=wq*pv.z; acc[4*m+3]+=wq*pv.w;
      }
    }
    const float wI = pt[i + 1];
#pragma unroll
    for (int m = 0; m < 16; ++m) acc[m] *= wI;

    {
      const int j0 = (t & 3) * 16;
      for (int jn = 0; jn < 16; ++jn) {
        const int j = j0 + jn;
        float dot = 0.0f;
        const float4* kr = (const float4*)(ks + j * kD);
#pragma unroll
        for (int d4 = 0; d4 < 16; ++d4) {
          float4 kk = kr[d4];
          dot += qreg[4*d4+0]*kk.x + qreg[4*d4+1]*kk.y
               + qreg[4*d4+2]*kk.z + qreg[4*d4+3]*kk.w;
        }
        ss[i * 65 + j] = (j <= i) ? dot * pt[i - j] : 0.0f;
      }
    }
    __syncthreads();   // phase0 state reads done; scores visible

    {
      const int jmax = i | 15;
      for (int j = 0; j <= jmax; ++j) {
        const float w = ss[i * 65 + j];
        const float4* vr = (const float4*)(vs + j * kD + e0);
#pragma unroll
        for (int m = 0; m < 4; ++m) {
          float4 vv = vr[m];
          acc[4*m+0]+=w*vv.x; acc[4*m+1]+=w*vv.y; acc[4*m+2]+=w*vv.z; acc[4*m+3]+=w*vv.w;
        }
      }
    }

    {
      float4* ob = (float4*)(O + gbase + (size_t)i * kD + e0);
#pragma unroll
      for (int m = 0; m < 4; ++m)
        ob[m] = make_float4(kScale*acc[4*m+0], kScale*acc[4*m+1],
                            kScale*acc[4*m+2], kScale*acc[4*m+3]);
    }

    // State update: St = gC*St + sum_j gamma^(C-1-j) k[j][d] v[j][e]
    {
      float upd[16];
#pragma unroll
      for (int m = 0; m < 16; ++m) upd[m] = 0.0f;
      for (int j = 0; j < kC; ++j) {
        const float wk = pt[kC - 1 - j] * ks[j * kD + i];
        const float4* vr = (const float4*)(vs + j * kD + e0);
#pragma unroll
        for (int m = 0; m < 4; ++m) {
          float4 vv = vr[m];
          upd[4*m+0]+=wk*vv.x; upd[4*m+1]+=wk*vv.y; upd[4*m+2]+=wk*vv.z; upd[4*m+3]+=wk*vv.w;
        }
      }
#pragma unroll
      for (int m = 0; m < 16; ++m)
        St[i * kD + e0 + m] = gC * St[i * kD + e0 + m] + upd[m];
    }
    __syncthreads();
  }
}

// ---------------------------------------------------------------------------
extern "C" void kernel_launch(void* const* d_in, const int* in_sizes, int n_in,
                              void* d_out, int out_size, void* d_ws, size_t ws_size,
                              hipStream_t stream) {
  const float* q = (const float*)d_in[0];
  const float* k = (const float*)d_in[1];
  const float* v = (const float*)d_in[2];
  float* out = (float*)d_out;

  const size_t need = (size_t)kB * kH * kNC * kD * kD * sizeof(float); // 16 MiB
  if (ws_size >= need) {
    float* A = (float*)d_ws;
    ret_partial<<<kB * kH * kNC, 256, 0, stream>>>(k, v, A);
    ret_scan<<<kB * kH, 256, 0, stream>>>(A);
    ret_out<<<kB * kH * kNC, 256, 0, stream>>>(q, k, v, A, out);
  } else {
    ret_fallback<<<kB * kH, 256, 0, stream>>>(q, k, v, out);
  }
}